// Round 20
// baseline (182.289 us; speedup 1.0000x reference)
//
#include <hip/hip_runtime.h>
#include <stdint.h>

typedef unsigned short u16;
typedef __attribute__((ext_vector_type(4))) float f32x4;
typedef __attribute__((ext_vector_type(16))) float f32x16;
typedef __attribute__((ext_vector_type(8))) __bf16 bf16x8;
typedef __attribute__((ext_vector_type(8))) u16 u16x8;
typedef __attribute__((ext_vector_type(4))) u16 u16x4;
typedef __attribute__((ext_vector_type(2))) unsigned u32x2;

static constexpr int kB = 4, kS = 2048, kD = 1024, kH = 16, kHD = 64;
static constexpr int M1 = kB * kS;   // 8192
static constexpr int N1 = 3 * kD;    // 3072
static constexpr int K1 = kD;        // 1024

// 1/sqrt(64) * log2(e), folded into Q at GEMM1 epilogue
#define SCLF 0.18033688011112042f
#define MFMA16(a, b, c) __builtin_amdgcn_mfma_f32_16x16x32_bf16((a), (b), (c), 0, 0, 0)
#define MFMA32(a, b, c) __builtin_amdgcn_mfma_f32_32x32x16_bf16((a), (b), (c), 0, 0, 0)

union U4 { unsigned u[4]; bf16x8 v; };

__device__ __forceinline__ u16 f2bf(float f) {
  union { float f; uint32_t u; } c; c.f = f;
  uint32_t u = c.u + 0x7FFFu + ((c.u >> 16) & 1u);   // RNE
  return (u16)(u >> 16);
}

__device__ __forceinline__ unsigned pkbf(float a, float b) {
  union { __bf16 h[2]; unsigned u; } c;
  c.h[0] = (__bf16)a; c.h[1] = (__bf16)b;
  return c.u;
}

__device__ __forceinline__ float max3f(float a, float b, float c) {
  return fmaxf(fmaxf(a, b), c);   // fuses to v_max3_f32
}

__device__ __forceinline__ void gload_lds16(const u16* g, u16* l) {
  __builtin_amdgcn_global_load_lds(
      (const __attribute__((address_space(1))) unsigned int*)g,
      (__attribute__((address_space(3))) unsigned int*)l, 16, 0, 0);
}

// ---------------- merged prep kernel (cast x + transpose both weights) -------
// grid: [0,8192) cast x; [8192,11264) transpose w_qkv; [11264,12288) w_out
__global__ __launch_bounds__(256) void k_prep(const float* __restrict__ x,
                                              const float* __restrict__ w_qkv,
                                              const float* __restrict__ w_out,
                                              u16* __restrict__ x_bf,
                                              u16* __restrict__ wqkvT,
                                              u16* __restrict__ woutT) {
  const int bid = blockIdx.x;
  if (bid < 8192) {
    int i = (bid * 256 + threadIdx.x) * 4;
    f32x4 v = *(const f32x4*)(x + i);
    u16x4 r;
    r[0] = f2bf(v[0]); r[1] = f2bf(v[1]); r[2] = f2bf(v[2]); r[3] = f2bf(v[3]);
    *(u16x4*)(x_bf + i) = r;
    return;
  }
  __shared__ float t[32][33];
  const float* w; u16* wt; int N, idx;
  if (bid < 8192 + 3072) { idx = bid - 8192;  w = w_qkv; wt = wqkvT; N = N1; }
  else                   { idx = bid - 11264; w = w_out; wt = woutT; N = kD; }
  const int ntn = N >> 5;
  const int n0 = (idx % ntn) * 32, k0 = (idx / ntn) * 32;
  const int tx = threadIdx.x & 31, ty = threadIdx.x >> 5;
  for (int r = ty; r < 32; r += 8)
    t[r][tx] = w[(size_t)(k0 + r) * N + n0 + tx];
  __syncthreads();
  for (int r = ty; r < 32; r += 8)
    wt[(size_t)(n0 + r) * K1 + k0 + tx] = f2bf(t[tx][r]);
}

// ---------------- GEMM v6 (A row-major MxK, BT row-major NxK) ----------------
// BM=128, BN=256, BK=64; 512 threads = 8 waves (2M x 4N), 64x64 per wave.
// 3 LDS K-tile buffers, depth-2 prefetch, counted vmcnt(6), 2-phase barrier
// pairs per K-tile (R16 schedule). NEW (R20): 32x32x16 MFMA (2382 vs 2075 TF
// ubench, half the MFMA instructions). Frag maps (R3-R8 verified): A/B row=l31,
// k=hi*8+i; C col=l31 (B-free), row=(r&3)+8*(r>>2)+4*hi (A-free).
// LDS layout + granule-XOR swizzle unchanged; phase = 2 k-substeps of 16.
// MODE 0 V-columns (col0>=2048) write V transposed via direct u16x4 stores.
template <int MODE>
__global__ __launch_bounds__(512) void k_gemm_bt(const u16* __restrict__ A,
                                                 const u16* __restrict__ BT,
                                                 u16* __restrict__ obf,
                                                 float* __restrict__ of,
                                                 int M, int N, int K) {
  __shared__ __align__(16) u16 Asb[3][128 * 64];   // 48 KB
  __shared__ __align__(16) u16 Bsb[3][256 * 64];   // 96 KB

  const int tid = threadIdx.x;
  const int wave = tid >> 6, lane = tid & 63;
  const int l31 = lane & 31, hi = lane >> 5;

  const int bid = blockIdx.x;
  const int qch = gridDim.x >> 3;
  const int swz = (bid & 7) * qch + (bid >> 3);
  const int ntN = N >> 8;
  const int row0 = (swz / ntN) * 128, col0 = (swz % ntN) * 256;
  const int wm = (wave >> 2) * 64, wn = (wave & 3) * 64;

  f32x16 acc[2][2];
#pragma unroll
  for (int i = 0; i < 2; ++i)
#pragma unroll
    for (int j = 0; j < 2; ++j)
#pragma unroll
      for (int r = 0; r < 16; ++r) acc[i][j][r] = 0.f;

  const int lr = lane >> 3, ls = lane & 7;
  const u16* srcA[2];
#pragma unroll
  for (int j = 0; j < 2; ++j) {
    const int r = (wave * 2 + j) * 8 + lr;
    srcA[j] = A + (size_t)(row0 + r) * K + (ls ^ (r & 7)) * 8;
  }
  const u16* srcB[4];
#pragma unroll
  for (int j = 0; j < 4; ++j) {
    const int r = (wave * 4 + j) * 8 + lr;
    srcB[j] = BT + (size_t)(col0 + r) * K + (ls ^ (r & 7)) * 8;
  }

  const int nT = K >> 6;   // K-tiles of 64

  {
    // prologue: stage tiles 0,1; publish tile 0
#pragma unroll
    for (int j = 0; j < 2; ++j)
      gload_lds16(srcA[j], &Asb[0][(wave * 2 + j) * 512]);
#pragma unroll
    for (int j = 0; j < 4; ++j)
      gload_lds16(srcB[j], &Bsb[0][(wave * 4 + j) * 512]);
#pragma unroll
    for (int j = 0; j < 2; ++j)
      gload_lds16(srcA[j] + 64, &Asb[1][(wave * 2 + j) * 512]);
#pragma unroll
    for (int j = 0; j < 4; ++j)
      gload_lds16(srcB[j] + 64, &Bsb[1][(wave * 4 + j) * 512]);
    asm volatile("s_waitcnt vmcnt(6)" ::: "memory");
    __builtin_amdgcn_s_barrier();
  }

  for (int t = 0; t < nT; ++t) {
    const u16* As = &Asb[t % 3][0];
    const u16* Bs = &Bsb[t % 3][0];
    const bool pf = (t + 2 < nT);
    const int buf2 = (t + 2) % 3;
    const int kt2 = (t + 2) * 64;
    bf16x8 af[2][2], bfv[2][2];   // [k-substep][frag]

    // ================= phase 0 (k substeps 0,1) =================
#pragma unroll
    for (int kkp = 0; kkp < 2; ++kkp) {
      const int g = kkp * 2 + hi;           // granule for k = kkp*16 + hi*8
#pragma unroll
      for (int f = 0; f < 2; ++f) {
        const int ra = wm + f * 32 + l31;
        af[kkp][f] = *(const bf16x8*)&As[ra * 64 + ((g ^ (ra & 7)) * 8)];
        const int rb = wn + f * 32 + l31;
        bfv[kkp][f] = *(const bf16x8*)&Bs[rb * 64 + ((g ^ (rb & 7)) * 8)];
      }
    }
    if (pf) {
      gload_lds16(srcA[0] + kt2, &Asb[buf2][(wave * 2 + 0) * 512]);
      gload_lds16(srcA[1] + kt2, &Asb[buf2][(wave * 2 + 1) * 512]);
      gload_lds16(srcB[0] + kt2, &Bsb[buf2][(wave * 4 + 0) * 512]);
    }
    __builtin_amdgcn_sched_barrier(0);
    __builtin_amdgcn_s_barrier();
    asm volatile("s_waitcnt lgkmcnt(0)" ::: "memory");
    __builtin_amdgcn_sched_barrier(0);   // pin MFMA below the wait (#18)
    __builtin_amdgcn_s_setprio(1);
#pragma unroll
    for (int kkp = 0; kkp < 2; ++kkp)
#pragma unroll
      for (int fm = 0; fm < 2; ++fm)
#pragma unroll
        for (int fn = 0; fn < 2; ++fn)
          acc[fm][fn] = MFMA32(af[kkp][fm], bfv[kkp][fn], acc[fm][fn]);
    __builtin_amdgcn_s_setprio(0);
    __builtin_amdgcn_sched_barrier(0);
    __builtin_amdgcn_s_barrier();

    // ================= phase 1 (k substeps 2,3) =================
#pragma unroll
    for (int kkp = 0; kkp < 2; ++kkp) {
      const int g = 4 + kkp * 2 + hi;
#pragma unroll
      for (int f = 0; f < 2; ++f) {
        const int ra = wm + f * 32 + l31;
        af[kkp][f] = *(const bf16x8*)&As[ra * 64 + ((g ^ (ra & 7)) * 8)];
        const int rb = wn + f * 32 + l31;
        bfv[kkp][f] = *(const bf16x8*)&Bs[rb * 64 + ((g ^ (rb & 7)) * 8)];
      }
    }
    if (pf) {
      gload_lds16(srcB[1] + kt2, &Bsb[buf2][(wave * 4 + 1) * 512]);
      gload_lds16(srcB[2] + kt2, &Bsb[buf2][(wave * 4 + 2) * 512]);
      gload_lds16(srcB[3] + kt2, &Bsb[buf2][(wave * 4 + 3) * 512]);
    }
    // tile t+1 publish (counted; only drains fully when no t+2 in flight)
    if (pf)                asm volatile("s_waitcnt vmcnt(6)" ::: "memory");
    else if (t + 1 < nT)   asm volatile("s_waitcnt vmcnt(0)" ::: "memory");
    __builtin_amdgcn_sched_barrier(0);
    __builtin_amdgcn_s_barrier();
    asm volatile("s_waitcnt lgkmcnt(0)" ::: "memory");
    __builtin_amdgcn_sched_barrier(0);
    __builtin_amdgcn_s_setprio(1);
#pragma unroll
    for (int kkp = 0; kkp < 2; ++kkp)
#pragma unroll
      for (int fm = 0; fm < 2; ++fm)
#pragma unroll
        for (int fn = 0; fn < 2; ++fn)
          acc[fm][fn] = MFMA32(af[kkp][fm], bfv[kkp][fn], acc[fm][fn]);
    __builtin_amdgcn_s_setprio(0);
    __builtin_amdgcn_sched_barrier(0);
    __builtin_amdgcn_s_barrier();
  }

  if (MODE == 0 && col0 >= 2048) {
    // ---- V block: direct VT[b][h][hd][s] stores; (r&3)-axis contiguous in s
    const int b = row0 >> 11, sbase = row0 & 2047;
#pragma unroll
    for (int fm = 0; fm < 2; ++fm)
#pragma unroll
      for (int fn = 0; fn < 2; ++fn) {
        const int d = (col0 + wn + fn * 32 + l31) & 1023;
        u16* drow = obf +
            ((((size_t)8 + b) * 16 + (d >> 6)) * 64 + (d & 63)) * 2048;
#pragma unroll
        for (int g2 = 0; g2 < 4; ++g2) {
          const int s = sbase + wm + fm * 32 + 8 * g2 + 4 * hi;
          u16x4 pk;
#pragma unroll
          for (int j = 0; j < 4; ++j) pk[j] = f2bf(acc[fm][fn][g2 * 4 + j]);
          *(u16x4*)(drow + s) = pk;
        }
      }
    return;
  }

#pragma unroll
  for (int fm = 0; fm < 2; ++fm)
#pragma unroll
    for (int fn = 0; fn < 2; ++fn) {
      const int n = col0 + wn + fn * 32 + l31;
#pragma unroll
      for (int r = 0; r < 16; ++r) {
        const int m = row0 + wm + fm * 32 + (r & 3) + 8 * (r >> 2) + 4 * hi;
        float v = acc[fm][fn][r];
        if constexpr (MODE == 0) {
          const int which = n >> 10, d = n & 1023;
          const int h = d >> 6, hd = d & 63;
          const int b = m >> 11, s = m & 2047;
          if (which == 0) v *= SCLF;   // fold softmax scale (log2 dom) into Q
          obf[((((size_t)which * 4 + b) * 16 + h) * 2048 + s) * 64 + hd] = f2bf(v);
        } else {
          of[(size_t)m * N + n] = v;
        }
      }
    }
}

// ---------------- flash attention v17 (KVBLK=128, per-half R18 V layout) -----
// R19 structure; Vs split into per-half [64x64] sub-buffers with the R18
// conflict-proven layout (R19's [d][128] rows tripled bank conflicts).
// Go/no-go: absmax ~0.0156, VGPR ~56, WRITE_SIZE 16.4MB, conflicts ~2.1M.
__global__ __launch_bounds__(512, 4) void k_attn(const u16* __restrict__ Qg,
                                                 const u16* __restrict__ Kg,
                                                 const u16* __restrict__ Vg,
                                                 u16* __restrict__ ctx) {
  __shared__ __align__(16) u16 Ks[2][128 * 64];       // 32 KB
  __shared__ __align__(16) u16 Vs[2][2][64 * 64];     // 32 KB  per-half VT swz
  __shared__ __align__(16) unsigned Pl[8 * 256];      // 8 KB   per-wave P

  const int bid = blockIdx.x;
  const int xcd = bid & 7, i2 = bid >> 3;
  const int bh = xcd * 8 + (i2 & 7);
  const int p = i2 >> 3;                      // 0..7
  const int bb = bh >> 4, hh = bh & 15;
  const int tid = threadIdx.x;
  const int wave = tid >> 6, lane = tid & 63;
  const int l15 = lane & 15, l16 = lane >> 4;

  const u16* Qb = Qg + (size_t)bh * kS * kHD;
  const u16* Kb = Kg + (size_t)bh * kS * kHD;
  const u16* Vb = Vg + (size_t)bh * kS * kHD;   // VT: [64 d][2048 keys]

  const int kkey = tid >> 3, ksl = tid & 7;      // staging: row(0..63), slot
  unsigned* Pw = Pl + wave * 256 + l15 * 16;     // this lane's P row (q=l15)
  const int pm = ((l15 >> 1) & 3) << 2;          // P slot swizzle

  // A = ones(16x32) fragment for the l-sum MFMA (bf16 1.0 = 0x3F80)
  U4 onesu;
#pragma unroll
  for (int i = 0; i < 4; ++i) onesu.u[i] = 0x3F803F80u;
  const bf16x8 vones = onesu.v;

  // K: LDS[key][s^(key&7)] (key range 128: call r covers keys r*64+kkey,
  // (r*64+kkey)&7 == kkey&7). V: per-half R18 layout LDS[d][s^(d&7)].
  const u16* ksrc = Kb + (size_t)kkey * 64 + (ksl ^ (kkey & 7)) * 8;
  const u16* vsrc = Vb + (size_t)kkey * 2048 + (ksl ^ (kkey & 7)) * 8;

  for (int phase = 0; phase < 2; ++phase) {
    const int qsup = phase ? (15 - p) : p;
    const int qstart = qsup * 128 + wave * 16;
    const int ntiles = qsup + 1;               // 128-key tiles

    // Q B-frags: row q = qstart + l15, d = ds*32 + l16*8 + i
    bf16x8 bq[2];
#pragma unroll
    for (int ds = 0; ds < 2; ++ds)
      bq[ds] = *(const bf16x8*)(Qb + (size_t)(qstart + l15) * 64 + ds * 32 + l16 * 8);

    f32x4 acc[4];
#pragma unroll
    for (int i = 0; i < 4; ++i) acc[i] = f32x4{0.f, 0.f, 0.f, 0.f};
    f32x4 acc_l = f32x4{0.f, 0.f, 0.f, 0.f};
    float mrow = -3e38f;

    // phase-transition guard: prev phase's readers must be done before
    // prologue overwrites buffer 0 (round-4 race lesson; ntiles parity varies)
    __syncthreads();

    // ---- prologue: K(0), V(0) gloads (2 + 2 per thread) ----
#pragma unroll
    for (int r = 0; r < 2; ++r) {
      gload_lds16(ksrc + r * 4096, &Ks[0][r * 4096 + wave * 512]);
      gload_lds16(vsrc + r * 64, &Vs[0][r][wave * 512]);
    }

    for (int t = 0; t < ntiles; ++t) {
      const int kv0 = t * 128;
      __syncthreads();  // drains K(t)/V(t) gloads; prev reads done

      if (t + 1 < ntiles) {
        const int nb = (t + 1) & 1;
#pragma unroll
        for (int r = 0; r < 2; ++r) {
          gload_lds16(ksrc + (size_t)(t + 1) * 8192 + r * 4096,
                      &Ks[nb][r * 4096 + wave * 512]);
          gload_lds16(vsrc + (size_t)(t + 1) * 128 + r * 64,
                      &Vs[nb][r][wave * 512]);
        }
      }

      if (kv0 > qstart + 15) continue;  // wave-uniform skip (barrier done above)

      const u16* Ksb = &Ks[t & 1][0];
      const int qv = qstart + l15;

#pragma unroll
      for (int h = 0; h < 2; ++h) {
        const int kb = kv0 + 64 * h;
        if (kb > qstart + 15) continue;  // half fully masked (wave-uniform)
        const u16* Vtb = &Vs[t & 1][h][0];
        const int kr = h * 64;           // key-row base in Ks
        const bool have1 = (kb + 32 <= qstart + 15);  // wave-uniform

        // ---- QK^T both chunks hoisted (chunk0: keys kb.., chunk1: +32) ----
        f32x4 stA0 = f32x4{0.f, 0.f, 0.f, 0.f}, stA1 = stA0;
        f32x4 stB0 = stA0, stB1 = stA0;
        __builtin_amdgcn_s_setprio(1);
#pragma unroll
        for (int ds = 0; ds < 2; ++ds) {
          const int slot = ((ds * 4 + l16) ^ (l15 & 7)) * 8;
          bf16x8 ak0 = *(const bf16x8*)&Ksb[(kr + l15) * 64 + slot];
          stA0 = MFMA16(ak0, bq[ds], stA0);
          bf16x8 ak1 = *(const bf16x8*)&Ksb[(kr + 16 + l15) * 64 + slot];
          stA1 = MFMA16(ak1, bq[ds], stA1);
          if (have1) {
            bf16x8 bk0 = *(const bf16x8*)&Ksb[(kr + 32 + l15) * 64 + slot];
            stB0 = MFMA16(bk0, bq[ds], stB0);
            bf16x8 bk1 = *(const bf16x8*)&Ksb[(kr + 48 + l15) * 64 + slot];
            stB1 = MFMA16(bk1, bq[ds], stB1);
          }
        }
        __builtin_amdgcn_s_setprio(0);

        // ---- joint mask (boundary-only) ----
        if (kb + 31 > qstart) {
#pragma unroll
          for (int j = 0; j < 4; ++j) {
            const int key = kb + l16 * 4 + j;
            stA0[j] = (key <= qv) ? stA0[j] : -3e38f;
            stA1[j] = (key + 16 <= qv) ? stA1[j] : -3e38f;
          }
        }
        if (have1 && (kb + 63 > qstart)) {
#pragma unroll
          for (int j = 0; j < 4; ++j) {
            const int key = kb + 32 + l16 * 4 + j;
            stB0[j] = (key <= qv) ? stB0[j] : -3e38f;
            stB1[j] = (key + 16 <= qv) ? stB1[j] : -3e38f;
          }
        }

        // ---- joint lane-partial max (max3-shaped trees) ----
        float tl;
        {
          const float mA = fmaxf(max3f(stA0[0], stA0[1], stA0[2]),
                                 max3f(stA0[3], stA1[0], stA1[1]));
          tl = max3f(stA1[2], stA1[3], mA);
          if (have1) {
            const float mB = fmaxf(max3f(stB0[0], stB0[1], stB0[2]),
                                   max3f(stB0[3], stB1[0], stB1[1]));
            tl = fmaxf(tl, max3f(stB1[2], stB1[3], mB));
          }
        }

        // ---- ONE defer-max decision per 64-key half ----
        float mn;
        if (__all(tl <= mrow + 8.0f)) {
          mn = mrow;
        } else {
          float tj = fmaxf(tl, __shfl_xor(tl, 16, 64));
          tj = fmaxf(tj, __shfl_xor(tj, 32, 64));
          mn = fmaxf(mrow, tj);
          const float al = exp2f(mrow - mn);
          mrow = mn;
          acc_l[0] *= al;
#pragma unroll
          for (int i = 0; i < 4; ++i)
#pragma unroll
            for (int j = 0; j < 4; ++j) acc[i][j] *= al;
        }

        // ---- chunk 0: exp, pack->LDS->frag, l-MFMA, PV ----
        {
#pragma unroll
          for (int j = 0; j < 4; ++j) {
            stA0[j] = exp2f(stA0[j] - mn);
            stA1[j] = exp2f(stA1[j] - mn);
          }
          const unsigned p0 = pkbf(stA0[0], stA0[1]);
          const unsigned p1 = pkbf(stA0[2], stA0[3]);
          const unsigned p2 = pkbf(stA1[0], stA1[1]);
          const unsigned p3 = pkbf(stA1[2], stA1[3]);
          *(u32x2*)&Pw[(l16 * 2) ^ pm] = u32x2{p0, p1};
          *(u32x2*)&Pw[(8 + l16 * 2) ^ pm] = u32x2{p2, p3};
          U4 f;
          f = *(const U4*)&Pw[(l16 * 4) ^ pm];
          __builtin_amdgcn_s_setprio(1);
          acc_l = MFMA16(vones, f.v, acc_l);   // l += sum_k P[k][q]
#pragma unroll
          for (int dg = 0; dg < 4; ++dg) {
            const int d = dg * 16 + l15;
            const bf16x8 vf =
                *(const bf16x8*)&Vtb[d * 64 + ((l16 ^ (d & 7)) * 8)];
            acc[dg] = MFMA16(vf, f.v, acc[dg]);
          }
          __builtin_amdgcn_s_setprio(0);
        }
        // ---- chunk 1 ----
        if (have1) {
#pragma unroll
          for (int j = 0; j < 4; ++j) {
            stB0[j] = exp2f(stB0[j] - mn);
            stB1[j] = exp2f(stB1[j] - mn);
          }
          const unsigned p0 = pkbf(stB0[0], stB0[1]);
          const unsigned p1 = pkbf(stB0[2], stB0[3]);
          const unsigned p2 = pkbf(stB1[0], stB1[1]);
          const unsigned p3 = pkbf(stB1[2], stB1[3]);
          *(u32x2*)&Pw[(l16 * 2) ^ pm] = u32x2{p0, p1};
          *(u32x2*)&Pw[(8 + l16 * 2) ^ pm] = u32x2{p2, p3};
          U4 f;
          f = *(const U4*)&Pw[(l16 * 4) ^ pm];
          __builtin_amdgcn_s_setprio(1);
          acc_l = MFMA16(vones, f.v, acc_l);   // l += sum_k P[k][q]
#pragma unroll
          for (int dg = 0; dg < 4; ++dg) {
            const int d = dg * 16 + l15;
            const bf16x8 vf =
                *(const bf16x8*)&Vtb[d * 64 + (((4 + l16) ^ (d & 7)) * 8)];
            acc[dg] = MFMA16(vf, f.v, acc[dg]);
          }
          __builtin_amdgcn_s_setprio(0);
        }
      }
    }

    // ---- epilogue: l is complete in acc_l[0] (summed over all keys) ----
    const float rl = 1.0f / acc_l[0];
    u16* orow = ctx + ((size_t)bb * kS + (qstart + l15)) * kD + hh * 64;
#pragma unroll
    for (int dg = 0; dg < 4; ++dg) {
      u16x4 pk;
#pragma unroll
      for (int j = 0; j < 4; ++j) pk[j] = f2bf(acc[dg][j] * rl);
      *(u16x4*)&orow[dg * 16 + l16 * 4] = pk;
    }
  }
}

// ---------------- launcher ----------------
extern "C" void kernel_launch(void* const* d_in, const int* in_sizes, int n_in,
                              void* d_out, int out_size, void* d_ws, size_t ws_size,
                              hipStream_t stream) {
  const float* x     = (const float*)d_in[0];
  const float* w_qkv = (const float*)d_in[1];
  const float* w_out = (const float*)d_in[2];
  float* out = (float*)d_out;

  u16* ws    = (u16*)d_ws;
  u16* x_bf  = ws;                                  // 8192*1024
  u16* wqkvT = x_bf + (size_t)M1 * K1;              // 3072*1024
  u16* woutT = wqkvT + (size_t)N1 * K1;             // 1024*1024
  u16* qkv   = woutT + (size_t)kD * kD;             // 3 * 64*2048*64 (V region transposed)
  u16* ctx   = qkv + (size_t)3 * kB * kH * kS * kHD;  // 8192*1024

  k_prep<<<dim3(12288), 256, 0, stream>>>(x, w_qkv, w_out, x_bf, wqkvT, woutT);

  // BM=128, BN=256: GEMM1 grid = 64*12 = 768 = 3/CU exact; GEMM2 = 64*4 = 256
  k_gemm_bt<0><<<dim3(768), 512, 0, stream>>>(x_bf, wqkvT, qkv, nullptr,
                                              M1, N1, K1);

  const u16* Qg = qkv;
  const u16* Kg = qkv + (size_t)kB * kH * kS * kHD;
  const u16* Vg = qkv + (size_t)2 * kB * kH * kS * kHD;   // [bh][64 d][2048 s]
  k_attn<<<dim3(512), 512, 0, stream>>>(Qg, Kg, Vg, ctx);

  k_gemm_bt<1><<<dim3(256), 512, 0, stream>>>(ctx, woutT, nullptr, out,
                                              M1, kD, K1);
}

// Round 21
// 173.907 us; speedup vs baseline: 1.0482x; 1.0482x over previous
//
#include <hip/hip_runtime.h>
#include <stdint.h>

typedef unsigned short u16;
typedef __attribute__((ext_vector_type(4))) float f32x4;
typedef __attribute__((ext_vector_type(8))) __bf16 bf16x8;
typedef __attribute__((ext_vector_type(8))) u16 u16x8;
typedef __attribute__((ext_vector_type(4))) u16 u16x4;
typedef __attribute__((ext_vector_type(2))) unsigned u32x2;

static constexpr int kB = 4, kS = 2048, kD = 1024, kH = 16, kHD = 64;
static constexpr int M1 = kB * kS;   // 8192
static constexpr int N1 = 3 * kD;    // 3072
static constexpr int K1 = kD;        // 1024

// 1/sqrt(64) * log2(e), folded into Q at GEMM1 epilogue
#define SCLF 0.18033688011112042f
#define MFMA16(a, b, c) __builtin_amdgcn_mfma_f32_16x16x32_bf16((a), (b), (c), 0, 0, 0)

union U4 { unsigned u[4]; bf16x8 v; };

__device__ __forceinline__ u16 f2bf(float f) {
  union { float f; uint32_t u; } c; c.f = f;
  uint32_t u = c.u + 0x7FFFu + ((c.u >> 16) & 1u);   // RNE
  return (u16)(u >> 16);
}

__device__ __forceinline__ unsigned pkbf(float a, float b) {
  union { __bf16 h[2]; unsigned u; } c;
  c.h[0] = (__bf16)a; c.h[1] = (__bf16)b;
  return c.u;
}

__device__ __forceinline__ float max3f(float a, float b, float c) {
  return fmaxf(fmaxf(a, b), c);   // fuses to v_max3_f32
}

__device__ __forceinline__ void gload_lds16(const u16* g, u16* l) {
  __builtin_amdgcn_global_load_lds(
      (const __attribute__((address_space(1))) unsigned int*)g,
      (__attribute__((address_space(3))) unsigned int*)l, 16, 0, 0);
}

// ---------------- merged prep kernel (cast x + transpose both weights) -------
// grid: [0,8192) cast x; [8192,11264) transpose w_qkv; [11264,12288) w_out
__global__ __launch_bounds__(256) void k_prep(const float* __restrict__ x,
                                              const float* __restrict__ w_qkv,
                                              const float* __restrict__ w_out,
                                              u16* __restrict__ x_bf,
                                              u16* __restrict__ wqkvT,
                                              u16* __restrict__ woutT) {
  const int bid = blockIdx.x;
  if (bid < 8192) {
    int i = (bid * 256 + threadIdx.x) * 4;
    f32x4 v = *(const f32x4*)(x + i);
    u16x4 r;
    r[0] = f2bf(v[0]); r[1] = f2bf(v[1]); r[2] = f2bf(v[2]); r[3] = f2bf(v[3]);
    *(u16x4*)(x_bf + i) = r;
    return;
  }
  __shared__ float t[32][33];
  const float* w; u16* wt; int N, idx;
  if (bid < 8192 + 3072) { idx = bid - 8192;  w = w_qkv; wt = wqkvT; N = N1; }
  else                   { idx = bid - 11264; w = w_out; wt = woutT; N = kD; }
  const int ntn = N >> 5;
  const int n0 = (idx % ntn) * 32, k0 = (idx / ntn) * 32;
  const int tx = threadIdx.x & 31, ty = threadIdx.x >> 5;
  for (int r = ty; r < 32; r += 8)
    t[r][tx] = w[(size_t)(k0 + r) * N + n0 + tx];
  __syncthreads();
  for (int r = ty; r < 32; r += 8)
    wt[(size_t)(n0 + r) * K1 + k0 + tx] = f2bf(t[tx][r]);
}

// ---------------- GEMM v5 (A row-major MxK, BT row-major NxK) ----------------
// (R18/R19 version — 16x16x32 MFMA; R20's 32x32 variant regressed ~8us: less
// MFMA time per barrier-pair phase -> fixed phase overhead dominated.)
// BM=128, BN=256, BK=64; 512 threads = 8 waves (2M x 4N), 64x64 per wave.
// 3 LDS K-tile buffers, depth-2 prefetch, counted vmcnt(6), 2-phase barrier
// pairs per K-tile. MODE 0 V-columns (col0>=2048) write V transposed
// [b][h][d][s] via direct u16x4 stores (j-axis contiguous in s).
template <int MODE>
__global__ __launch_bounds__(512) void k_gemm_bt(const u16* __restrict__ A,
                                                 const u16* __restrict__ BT,
                                                 u16* __restrict__ obf,
                                                 float* __restrict__ of,
                                                 int M, int N, int K) {
  __shared__ __align__(16) u16 Asb[3][128 * 64];   // 48 KB
  __shared__ __align__(16) u16 Bsb[3][256 * 64];   // 96 KB

  const int tid = threadIdx.x;
  const int wave = tid >> 6, lane = tid & 63;
  const int l15 = lane & 15, l16 = lane >> 4;

  const int bid = blockIdx.x;
  const int qch = gridDim.x >> 3;
  const int swz = (bid & 7) * qch + (bid >> 3);
  const int ntN = N >> 8;
  const int row0 = (swz / ntN) * 128, col0 = (swz % ntN) * 256;
  const int wm = (wave >> 2) * 64, wn = (wave & 3) * 64;

  f32x4 acc[4][4];
#pragma unroll
  for (int i = 0; i < 4; ++i)
#pragma unroll
    for (int j = 0; j < 4; ++j) acc[i][j] = f32x4{0.f, 0.f, 0.f, 0.f};

  const int lr = lane >> 3, ls = lane & 7;
  const u16* srcA[2];
#pragma unroll
  for (int j = 0; j < 2; ++j) {
    const int r = (wave * 2 + j) * 8 + lr;
    srcA[j] = A + (size_t)(row0 + r) * K + (ls ^ (r & 7)) * 8;
  }
  const u16* srcB[4];
#pragma unroll
  for (int j = 0; j < 4; ++j) {
    const int r = (wave * 4 + j) * 8 + lr;
    srcB[j] = BT + (size_t)(col0 + r) * K + (ls ^ (r & 7)) * 8;
  }

  const int nT = K >> 6;   // K-tiles of 64

  {
    // prologue: stage tiles 0,1; publish tile 0
#pragma unroll
    for (int j = 0; j < 2; ++j)
      gload_lds16(srcA[j], &Asb[0][(wave * 2 + j) * 512]);
#pragma unroll
    for (int j = 0; j < 4; ++j)
      gload_lds16(srcB[j], &Bsb[0][(wave * 4 + j) * 512]);
#pragma unroll
    for (int j = 0; j < 2; ++j)
      gload_lds16(srcA[j] + 64, &Asb[1][(wave * 2 + j) * 512]);
#pragma unroll
    for (int j = 0; j < 4; ++j)
      gload_lds16(srcB[j] + 64, &Bsb[1][(wave * 4 + j) * 512]);
    asm volatile("s_waitcnt vmcnt(6)" ::: "memory");
    __builtin_amdgcn_s_barrier();
  }

  for (int t = 0; t < nT; ++t) {
    const u16* As = &Asb[t % 3][0];
    const u16* Bs = &Bsb[t % 3][0];
    const bool pf = (t + 2 < nT);
    const int buf2 = (t + 2) % 3;
    const int kt2 = (t + 2) * 64;
    bf16x8 af[4], bfv[4];

    // ================= phase 0 (kk = 0) =================
#pragma unroll
    for (int f = 0; f < 4; ++f) {
      const int ra = wm + f * 16 + l15;
      af[f] = *(const bf16x8*)&As[ra * 64 + ((l16 ^ (ra & 7)) * 8)];
      const int rb = wn + f * 16 + l15;
      bfv[f] = *(const bf16x8*)&Bs[rb * 64 + ((l16 ^ (rb & 7)) * 8)];
    }
    if (pf) {
      gload_lds16(srcA[0] + kt2, &Asb[buf2][(wave * 2 + 0) * 512]);
      gload_lds16(srcA[1] + kt2, &Asb[buf2][(wave * 2 + 1) * 512]);
      gload_lds16(srcB[0] + kt2, &Bsb[buf2][(wave * 4 + 0) * 512]);
    }
    __builtin_amdgcn_sched_barrier(0);
    __builtin_amdgcn_s_barrier();
    asm volatile("s_waitcnt lgkmcnt(0)" ::: "memory");
    __builtin_amdgcn_sched_barrier(0);   // pin MFMA below the wait (#18)
    __builtin_amdgcn_s_setprio(1);
#pragma unroll
    for (int fm = 0; fm < 4; ++fm)
#pragma unroll
      for (int fn = 0; fn < 4; ++fn)
        acc[fm][fn] = MFMA16(af[fm], bfv[fn], acc[fm][fn]);
    __builtin_amdgcn_s_setprio(0);
    __builtin_amdgcn_sched_barrier(0);
    __builtin_amdgcn_s_barrier();

    // ================= phase 1 (kk = 1) =================
#pragma unroll
    for (int f = 0; f < 4; ++f) {
      const int ra = wm + f * 16 + l15;
      af[f] = *(const bf16x8*)&As[ra * 64 + (((4 + l16) ^ (ra & 7)) * 8)];
      const int rb = wn + f * 16 + l15;
      bfv[f] = *(const bf16x8*)&Bs[rb * 64 + (((4 + l16) ^ (rb & 7)) * 8)];
    }
    if (pf) {
      gload_lds16(srcB[1] + kt2, &Bsb[buf2][(wave * 4 + 1) * 512]);
      gload_lds16(srcB[2] + kt2, &Bsb[buf2][(wave * 4 + 2) * 512]);
      gload_lds16(srcB[3] + kt2, &Bsb[buf2][(wave * 4 + 3) * 512]);
    }
    // tile t+1 publish (counted; only drains fully when no t+2 in flight)
    if (pf)                asm volatile("s_waitcnt vmcnt(6)" ::: "memory");
    else if (t + 1 < nT)   asm volatile("s_waitcnt vmcnt(0)" ::: "memory");
    __builtin_amdgcn_sched_barrier(0);
    __builtin_amdgcn_s_barrier();
    asm volatile("s_waitcnt lgkmcnt(0)" ::: "memory");
    __builtin_amdgcn_sched_barrier(0);
    __builtin_amdgcn_s_setprio(1);
#pragma unroll
    for (int fm = 0; fm < 4; ++fm)
#pragma unroll
      for (int fn = 0; fn < 4; ++fn)
        acc[fm][fn] = MFMA16(af[fm], bfv[fn], acc[fm][fn]);
    __builtin_amdgcn_s_setprio(0);
    __builtin_amdgcn_sched_barrier(0);
    __builtin_amdgcn_s_barrier();
  }

  if (MODE == 0 && col0 >= 2048) {
    // ---- V block: direct VT[b][h][hd][s] stores; j-axis contiguous in s ----
    const int b = row0 >> 11, sbase = row0 & 2047;
#pragma unroll
    for (int fm = 0; fm < 4; ++fm)
#pragma unroll
      for (int fn = 0; fn < 4; ++fn) {
        const int d = (col0 + wn + fn * 16 + l15) & 1023;
        const int s = sbase + wm + fm * 16 + l16 * 4;
        u16x4 pk;
#pragma unroll
        for (int j = 0; j < 4; ++j) pk[j] = f2bf(acc[fm][fn][j]);
        *(u16x4*)(obf +
                  ((((size_t)8 + b) * 16 + (d >> 6)) * 64 + (d & 63)) * 2048 +
                  s) = pk;
      }
    return;
  }

#pragma unroll
  for (int fm = 0; fm < 4; ++fm)
#pragma unroll
    for (int fn = 0; fn < 4; ++fn) {
      const int n = col0 + wn + fn * 16 + l15;
#pragma unroll
      for (int j = 0; j < 4; ++j) {
        const int m = row0 + wm + fm * 16 + l16 * 4 + j;
        float v = acc[fm][fn][j];
        if constexpr (MODE == 0) {
          const int which = n >> 10, d = n & 1023;
          const int h = d >> 6, hd = d & 63;
          const int b = m >> 11, s = m & 2047;
          if (which == 0) v *= SCLF;   // fold softmax scale (log2 dom) into Q
          obf[((((size_t)which * 4 + b) * 16 + h) * 2048 + s) * 64 + hd] = f2bf(v);
        } else {
          of[(size_t)m * N + n] = v;
        }
      }
    }
}

// ---------------- flash attention v17 (KVBLK=128, per-half R18 V layout) -----
// (R20's attn — best measured: 85.2us, conflicts 2.1M, VGPR 56.)
__global__ __launch_bounds__(512, 4) void k_attn(const u16* __restrict__ Qg,
                                                 const u16* __restrict__ Kg,
                                                 const u16* __restrict__ Vg,
                                                 u16* __restrict__ ctx) {
  __shared__ __align__(16) u16 Ks[2][128 * 64];       // 32 KB
  __shared__ __align__(16) u16 Vs[2][2][64 * 64];     // 32 KB  per-half VT swz
  __shared__ __align__(16) unsigned Pl[8 * 256];      // 8 KB   per-wave P

  const int bid = blockIdx.x;
  const int xcd = bid & 7, i2 = bid >> 3;
  const int bh = xcd * 8 + (i2 & 7);
  const int p = i2 >> 3;                      // 0..7
  const int bb = bh >> 4, hh = bh & 15;
  const int tid = threadIdx.x;
  const int wave = tid >> 6, lane = tid & 63;
  const int l15 = lane & 15, l16 = lane >> 4;

  const u16* Qb = Qg + (size_t)bh * kS * kHD;
  const u16* Kb = Kg + (size_t)bh * kS * kHD;
  const u16* Vb = Vg + (size_t)bh * kS * kHD;   // VT: [64 d][2048 keys]

  const int kkey = tid >> 3, ksl = tid & 7;      // staging: row(0..63), slot
  unsigned* Pw = Pl + wave * 256 + l15 * 16;     // this lane's P row (q=l15)
  const int pm = ((l15 >> 1) & 3) << 2;          // P slot swizzle

  // A = ones(16x32) fragment for the l-sum MFMA (bf16 1.0 = 0x3F80)
  U4 onesu;
#pragma unroll
  for (int i = 0; i < 4; ++i) onesu.u[i] = 0x3F803F80u;
  const bf16x8 vones = onesu.v;

  // K: LDS[key][s^(key&7)] (key range 128: call r covers keys r*64+kkey,
  // (r*64+kkey)&7 == kkey&7). V: per-half R18 layout LDS[d][s^(d&7)].
  const u16* ksrc = Kb + (size_t)kkey * 64 + (ksl ^ (kkey & 7)) * 8;
  const u16* vsrc = Vb + (size_t)kkey * 2048 + (ksl ^ (kkey & 7)) * 8;

  for (int phase = 0; phase < 2; ++phase) {
    const int qsup = phase ? (15 - p) : p;
    const int qstart = qsup * 128 + wave * 16;
    const int ntiles = qsup + 1;               // 128-key tiles

    // Q B-frags: row q = qstart + l15, d = ds*32 + l16*8 + i
    bf16x8 bq[2];
#pragma unroll
    for (int ds = 0; ds < 2; ++ds)
      bq[ds] = *(const bf16x8*)(Qb + (size_t)(qstart + l15) * 64 + ds * 32 + l16 * 8);

    f32x4 acc[4];
#pragma unroll
    for (int i = 0; i < 4; ++i) acc[i] = f32x4{0.f, 0.f, 0.f, 0.f};
    f32x4 acc_l = f32x4{0.f, 0.f, 0.f, 0.f};
    float mrow = -3e38f;

    // phase-transition guard: prev phase's readers must be done before
    // prologue overwrites buffer 0 (round-4 race lesson; ntiles parity varies)
    __syncthreads();

    // ---- prologue: K(0), V(0) gloads (2 + 2 per thread) ----
#pragma unroll
    for (int r = 0; r < 2; ++r) {
      gload_lds16(ksrc + r * 4096, &Ks[0][r * 4096 + wave * 512]);
      gload_lds16(vsrc + r * 64, &Vs[0][r][wave * 512]);
    }

    for (int t = 0; t < ntiles; ++t) {
      const int kv0 = t * 128;
      __syncthreads();  // drains K(t)/V(t) gloads; prev reads done

      if (t + 1 < ntiles) {
        const int nb = (t + 1) & 1;
#pragma unroll
        for (int r = 0; r < 2; ++r) {
          gload_lds16(ksrc + (size_t)(t + 1) * 8192 + r * 4096,
                      &Ks[nb][r * 4096 + wave * 512]);
          gload_lds16(vsrc + (size_t)(t + 1) * 128 + r * 64,
                      &Vs[nb][r][wave * 512]);
        }
      }

      if (kv0 > qstart + 15) continue;  // wave-uniform skip (barrier done above)

      const u16* Ksb = &Ks[t & 1][0];
      const int qv = qstart + l15;

#pragma unroll
      for (int h = 0; h < 2; ++h) {
        const int kb = kv0 + 64 * h;
        if (kb > qstart + 15) continue;  // half fully masked (wave-uniform)
        const u16* Vtb = &Vs[t & 1][h][0];
        const int kr = h * 64;           // key-row base in Ks
        const bool have1 = (kb + 32 <= qstart + 15);  // wave-uniform

        // ---- QK^T both chunks hoisted (chunk0: keys kb.., chunk1: +32) ----
        f32x4 stA0 = f32x4{0.f, 0.f, 0.f, 0.f}, stA1 = stA0;
        f32x4 stB0 = stA0, stB1 = stA0;
        __builtin_amdgcn_s_setprio(1);
#pragma unroll
        for (int ds = 0; ds < 2; ++ds) {
          const int slot = ((ds * 4 + l16) ^ (l15 & 7)) * 8;
          bf16x8 ak0 = *(const bf16x8*)&Ksb[(kr + l15) * 64 + slot];
          stA0 = MFMA16(ak0, bq[ds], stA0);
          bf16x8 ak1 = *(const bf16x8*)&Ksb[(kr + 16 + l15) * 64 + slot];
          stA1 = MFMA16(ak1, bq[ds], stA1);
          if (have1) {
            bf16x8 bk0 = *(const bf16x8*)&Ksb[(kr + 32 + l15) * 64 + slot];
            stB0 = MFMA16(bk0, bq[ds], stB0);
            bf16x8 bk1 = *(const bf16x8*)&Ksb[(kr + 48 + l15) * 64 + slot];
            stB1 = MFMA16(bk1, bq[ds], stB1);
          }
        }
        __builtin_amdgcn_s_setprio(0);

        // ---- joint mask (boundary-only) ----
        if (kb + 31 > qstart) {
#pragma unroll
          for (int j = 0; j < 4; ++j) {
            const int key = kb + l16 * 4 + j;
            stA0[j] = (key <= qv) ? stA0[j] : -3e38f;
            stA1[j] = (key + 16 <= qv) ? stA1[j] : -3e38f;
          }
        }
        if (have1 && (kb + 63 > qstart)) {
#pragma unroll
          for (int j = 0; j < 4; ++j) {
            const int key = kb + 32 + l16 * 4 + j;
            stB0[j] = (key <= qv) ? stB0[j] : -3e38f;
            stB1[j] = (key + 16 <= qv) ? stB1[j] : -3e38f;
          }
        }

        // ---- joint lane-partial max (max3-shaped trees) ----
        float tl;
        {
          const float mA = fmaxf(max3f(stA0[0], stA0[1], stA0[2]),
                                 max3f(stA0[3], stA1[0], stA1[1]));
          tl = max3f(stA1[2], stA1[3], mA);
          if (have1) {
            const float mB = fmaxf(max3f(stB0[0], stB0[1], stB0[2]),
                                   max3f(stB0[3], stB1[0], stB1[1]));
            tl = fmaxf(tl, max3f(stB1[2], stB1[3], mB));
          }
        }

        // ---- ONE defer-max decision per 64-key half ----
        float mn;
        if (__all(tl <= mrow + 8.0f)) {
          mn = mrow;
        } else {
          float tj = fmaxf(tl, __shfl_xor(tl, 16, 64));
          tj = fmaxf(tj, __shfl_xor(tj, 32, 64));
          mn = fmaxf(mrow, tj);
          const float al = exp2f(mrow - mn);
          mrow = mn;
          acc_l[0] *= al;
#pragma unroll
          for (int i = 0; i < 4; ++i)
#pragma unroll
            for (int j = 0; j < 4; ++j) acc[i][j] *= al;
        }

        // ---- chunk 0: exp, pack->LDS->frag, l-MFMA, PV ----
        {
#pragma unroll
          for (int j = 0; j < 4; ++j) {
            stA0[j] = exp2f(stA0[j] - mn);
            stA1[j] = exp2f(stA1[j] - mn);
          }
          const unsigned p0 = pkbf(stA0[0], stA0[1]);
          const unsigned p1 = pkbf(stA0[2], stA0[3]);
          const unsigned p2 = pkbf(stA1[0], stA1[1]);
          const unsigned p3 = pkbf(stA1[2], stA1[3]);
          *(u32x2*)&Pw[(l16 * 2) ^ pm] = u32x2{p0, p1};
          *(u32x2*)&Pw[(8 + l16 * 2) ^ pm] = u32x2{p2, p3};
          U4 f;
          f = *(const U4*)&Pw[(l16 * 4) ^ pm];
          __builtin_amdgcn_s_setprio(1);
          acc_l = MFMA16(vones, f.v, acc_l);   // l += sum_k P[k][q]
#pragma unroll
          for (int dg = 0; dg < 4; ++dg) {
            const int d = dg * 16 + l15;
            const bf16x8 vf =
                *(const bf16x8*)&Vtb[d * 64 + ((l16 ^ (d & 7)) * 8)];
            acc[dg] = MFMA16(vf, f.v, acc[dg]);
          }
          __builtin_amdgcn_s_setprio(0);
        }
        // ---- chunk 1 ----
        if (have1) {
#pragma unroll
          for (int j = 0; j < 4; ++j) {
            stB0[j] = exp2f(stB0[j] - mn);
            stB1[j] = exp2f(stB1[j] - mn);
          }
          const unsigned p0 = pkbf(stB0[0], stB0[1]);
          const unsigned p1 = pkbf(stB0[2], stB0[3]);
          const unsigned p2 = pkbf(stB1[0], stB1[1]);
          const unsigned p3 = pkbf(stB1[2], stB1[3]);
          *(u32x2*)&Pw[(l16 * 2) ^ pm] = u32x2{p0, p1};
          *(u32x2*)&Pw[(8 + l16 * 2) ^ pm] = u32x2{p2, p3};
          U4 f;
          f = *(const U4*)&Pw[(l16 * 4) ^ pm];
          __builtin_amdgcn_s_setprio(1);
          acc_l = MFMA16(vones, f.v, acc_l);   // l += sum_k P[k][q]
#pragma unroll
          for (int dg = 0; dg < 4; ++dg) {
            const int d = dg * 16 + l15;
            const bf16x8 vf =
                *(const bf16x8*)&Vtb[d * 64 + (((4 + l16) ^ (d & 7)) * 8)];
            acc[dg] = MFMA16(vf, f.v, acc[dg]);
          }
          __builtin_amdgcn_s_setprio(0);
        }
      }
    }

    // ---- epilogue: l is complete in acc_l[0] (summed over all keys) ----
    const float rl = 1.0f / acc_l[0];
    u16* orow = ctx + ((size_t)bb * kS + (qstart + l15)) * kD + hh * 64;
#pragma unroll
    for (int dg = 0; dg < 4; ++dg) {
      u16x4 pk;
#pragma unroll
      for (int j = 0; j < 4; ++j) pk[j] = f2bf(acc[dg][j] * rl);
      *(u16x4*)&orow[dg * 16 + l16 * 4] = pk;
    }
  }
}

// ---------------- launcher ----------------
extern "C" void kernel_launch(void* const* d_in, const int* in_sizes, int n_in,
                              void* d_out, int out_size, void* d_ws, size_t ws_size,
                              hipStream_t stream) {
  const float* x     = (const float*)d_in[0];
  const float* w_qkv = (const float*)d_in[1];
  const float* w_out = (const float*)d_in[2];
  float* out = (float*)d_out;

  u16* ws    = (u16*)d_ws;
  u16* x_bf  = ws;                                  // 8192*1024
  u16* wqkvT = x_bf + (size_t)M1 * K1;              // 3072*1024
  u16* woutT = wqkvT + (size_t)N1 * K1;             // 1024*1024
  u16* qkv   = woutT + (size_t)kD * kD;             // 3 * 64*2048*64 (V region transposed)
  u16* ctx   = qkv + (size_t)3 * kB * kH * kS * kHD;  // 8192*1024

  k_prep<<<dim3(12288), 256, 0, stream>>>(x, w_qkv, w_out, x_bf, wqkvT, woutT);

  // BM=128, BN=256: GEMM1 grid = 64*12 = 768 = 3/CU exact; GEMM2 = 64*4 = 256
  k_gemm_bt<0><<<dim3(768), 512, 0, stream>>>(x_bf, wqkvT, qkv, nullptr,
                                              M1, N1, K1);

  const u16* Qg = qkv;
  const u16* Kg = qkv + (size_t)kB * kH * kS * kHD;
  const u16* Vg = qkv + (size_t)2 * kB * kH * kS * kHD;   // [bh][64 d][2048 s]
  k_attn<<<dim3(512), 512, 0, stream>>>(Qg, Kg, Vg, ctx);

  k_gemm_bt<1><<<dim3(256), 512, 0, stream>>>(ctx, woutT, nullptr, out,
                                              M1, kD, K1);
}